// Round 10
// baseline (2422.961 us; speedup 1.0000x reference)
//
#include <hip/hip_runtime.h>
#include <hip/hip_bf16.h>
#include <math.h>

typedef __bf16 bf16;
typedef __bf16 bf16x8 __attribute__((ext_vector_type(8)));
typedef __bf16 bf16x4 __attribute__((ext_vector_type(4)));
typedef float f32x4 __attribute__((ext_vector_type(4)));
typedef float f32x16 __attribute__((ext_vector_type(16)));
typedef unsigned int u32;
typedef u32 u32x4 __attribute__((ext_vector_type(4)));

#define NINP 400
#define HS   1000
#define HP   1024
#define B_   8
#define T_   256
#define NT   2048   /* B_*T_ */
#define K2   2048   /* 2*HP  */
#define K1   1024   /* 2*512 */
#define M_   4096   /* 4 gates * HP */

#define HT_OFF   819200
#define CT_OFF   827200
#define AUX_OFF  835200

typedef __attribute__((address_space(1))) const void gvoid;
typedef __attribute__((address_space(3))) void lvoid;

__device__ __forceinline__ void async_copy16(void* lds, const void* g) {
  __builtin_amdgcn_global_load_lds((gvoid*)g, (lvoid*)lds, 16, 0, 0);
}

__device__ __forceinline__ float sigm(float x) { return 1.0f / (1.0f + expf(-x)); }

// ---------------- repack kernels (fp32 inputs -> packed-m bf16, row-major) ----------------
// m-packing (r8-verified): m = (h>>3)*32 + g*8 + (h&7).  32-row MFMA tile =
// 4 gates x 8 h; C-layout row=(reg&3)+8*(reg>>2)+4*(lane>>5) -> lane-local gating.

__global__ void repack_w1(const float* __restrict__ w1, bf16* __restrict__ W1q) {
  int idx = blockIdx.x * 256 + threadIdx.x;           // 4096*1024
  if (idx >= M_ * K1) return;
  int m = idx >> 10, k = idx & 1023;
  int g = (m >> 3) & 3, h = (m >> 5) * 8 + (m & 7);
  float v = 0.0f;
  if (h < HS) {
    int c = g * HS + h;
    if (k < 512) { if (k < NINP) v = w1[(size_t)c * (NINP * 2) + k * 2 + 0]; }
    else { int j = k - 512; if (j < NINP) v = w1[(size_t)c * (NINP * 2) + j * 2 + 1]; }
  }
  W1q[idx] = (bf16)v;
}

__global__ void repack_w2(const float* __restrict__ w2, bf16* __restrict__ W2q) {
  int idx = blockIdx.x * 256 + threadIdx.x;           // 4096*2048
  if (idx >= M_ * K2) return;
  int m = idx >> 11, k = idx & 2047;
  int g = (m >> 3) & 3, h = (m >> 5) * 8 + (m & 7);
  float v = 0.0f;
  if (h < HS) {
    int c = g * HS + h;
    if (k < HP) { if (k < HS) v = w2[(size_t)c * (HS * 2) + k * 2 + 0]; }
    else { int j = k - HP; if (j < HS) v = w2[(size_t)c * (HS * 2) + j * 2 + 1]; }
  }
  W2q[idx] = (bf16)v;
}

__global__ void build_xt(const float* __restrict__ X, bf16* __restrict__ XT) {
  int idx = blockIdx.x * 256 + threadIdx.x;           // 2048*1024
  if (idx >= NT * K1) return;
  int n = idx >> 10, k = idx & 1023;
  int b = n >> 8, t = n & (T_ - 1);
  float v = 0.0f;
  if (k < 512) { if (k < NINP && t > 0) v = X[((size_t)b * NINP + k) * T_ + t - 1]; }
  else { int j = k - 512; if (j < NINP) v = X[((size_t)b * NINP + j) * T_ + t]; }
  XT[idx] = (bf16)v;
}

__global__ void build_hc(const float* __restrict__ hid, const float* __restrict__ cell,
                         bf16* __restrict__ hidp, float* __restrict__ cellp) {
  int idx = blockIdx.x * 256 + threadIdx.x;           // 8*1024
  if (idx >= B_ * HP) return;
  int b = idx >> 10, k = idx & (HP - 1);
  hidp[idx]  = (k < HS) ? (bf16)hid[b * HS + k] : (bf16)0.0f;
  cellp[idx] = (k < HS) ? cell[b * HS + k] : 0.0f;
}

// ---------------- fused GEMM (+gating), 32x32x16, 64x64 waves, DMA staging ----------------
// Block 128M x 128N, 4 waves; wave (mh,nh) = (w>>1, w&1) owns 64x64 (2mt x 2nt
// of 32x32 tiles) -> LDS-read bytes/MAC halved vs 64x32 waves (r6).
// BK=64, single-buffered As/Bs (32 KB), r6's verified 2-barrier DMA loop with
// the r5 source-rotation swizzle: row r's logical 16B chunk l at phys (l+r)&7
// (staging reads global offset ((c8-dr)&7)*8); fragment reads rotate identically.
// CbP epilogue loads hoisted into registers BEFORE the K-loop (latency hidden).

template <bool GATED>
__global__ __launch_bounds__(256, 2) void gemm_step(
    const bf16* __restrict__ A,      // W2q [4096][2048] or W1q [4096][1024] packed-m
    const bf16* __restrict__ Bsrc,   // gated: Hprev [NT][HP]; plain: XT [NT][K1]
    const bf16* __restrict__ hidp,   // [B_][HP]
    const bf16* __restrict__ CbIn,   // gated: CbP [NT][4096] packed-m
    bf16* __restrict__ CbOut,        // plain: write CbP
    const float* __restrict__ b2,
    const bf16* __restrict__ ctprev, // [HP][NT]
    const float* __restrict__ cellp, // [B_][HP]
    bf16* __restrict__ ctnew,        // [HP][NT]
    bf16* __restrict__ Hnew,         // [NT][HP]
    int K) {
  __shared__ bf16 SMEM[2][128][64];  // [0]=As, [1]=Bs, 32 KB total; epilogue overlays

  const int tid = threadIdx.x;
  const int lane = tid & 63;
  const int w = tid >> 6;
  const int mh = w >> 1, nh = w & 1;
  const int dr = lane >> 3, c8 = lane & 7;
  const int swo = ((c8 - dr) & 7) * 8;     // staging source permutation
  const int row32 = lane & 31, q2 = lane >> 5;

  int n0, bm;
  if (GATED) {
    const int L = blockIdx.y * gridDim.x + blockIdx.x;
    bm = (L & 7) * 4 + (L >> 7);           // XCD L&7 owns 4 bm (2 MB W2q slice)
    n0 = ((L >> 3) & 15) * 128;
  } else {
    n0 = blockIdx.x * 128;
    bm = blockIdx.y;
  }

  f32x16 acc[2][2];
#pragma unroll
  for (int i = 0; i < 2; ++i)
#pragma unroll
    for (int j = 0; j < 2; ++j)
#pragma unroll
      for (int e = 0; e < 16; ++e) acc[i][j][e] = 0.0f;

  // Hoisted CbP loads (gated): 16x bf16x4, consumed only in the epilogue.
  bf16x4 cbr[2][2][4];
  if (GATED) {
#pragma unroll
    for (int mt = 0; mt < 2; ++mt) {
      const int tt = mh * 2 + mt;
#pragma unroll
      for (int nt = 0; nt < 2; ++nt) {
        const int n = n0 + nh * 64 + nt * 32 + row32;
        const size_t cb = (size_t)n * 4096 + (size_t)(bm * 4 + tt) * 32 + 4 * q2;
#pragma unroll
        for (int g = 0; g < 4; ++g)
          cbr[mt][nt][g] = *(const bf16x4*)&CbIn[cb + g * 8];
      }
    }
  }

  const int NIT = K >> 6;
  for (int it = 0; it < NIT; ++it) {
    const int k0 = it << 6;
    __syncthreads();                        // prev compute done; buffers reusable
#pragma unroll
    for (int inst = 0; inst < 4; ++inst) {
      const int r = inst * 32 + w * 8 + dr;
      // A staging: rows bm*128 + r of packed-m weights
      async_copy16(&SMEM[0][inst * 32 + w * 8][0],
                   A + (size_t)(bm * 128 + r) * K + k0 + swo);
      // B staging
      const int n = n0 + r;
      const bf16* bp;
      if (GATED) {
        const int kk = (k0 & (HP - 1)) + swo;
        if (k0 < HP) {
          const int t = n & (T_ - 1);
          bp = (t == 0) ? (hidp + (size_t)(n >> 8) * HP + kk)
                        : (Bsrc + (size_t)(n - 1) * HP + kk);
        } else {
          bp = Bsrc + (size_t)n * HP + kk;
        }
      } else {
        bp = Bsrc + (size_t)n * K + k0 + swo;
      }
      async_copy16(&SMEM[1][inst * 32 + w * 8][0], bp);
    }
    __syncthreads();                        // DMA drained (compiler emits vmcnt0)
#pragma unroll
    for (int kc = 0; kc < 4; ++kc) {
      const int l = kc * 2 + q2;
      bf16x8 av[2], bv[2];
#pragma unroll
      for (int mt = 0; mt < 2; ++mt) {
        const int r = mh * 64 + mt * 32 + row32;
        av[mt] = *(const bf16x8*)&SMEM[0][r][((l + r) & 7) * 8];
      }
#pragma unroll
      for (int nt = 0; nt < 2; ++nt) {
        const int r = nh * 64 + nt * 32 + row32;
        bv[nt] = *(const bf16x8*)&SMEM[1][r][((l + r) & 7) * 8];
      }
#pragma unroll
      for (int mt = 0; mt < 2; ++mt)
#pragma unroll
        for (int nt = 0; nt < 2; ++nt)
          acc[mt][nt] = __builtin_amdgcn_mfma_f32_32x32x16_bf16(av[mt], bv[nt], acc[mt][nt], 0, 0, 0);
    }
  }

  if (!GATED) {
    __syncthreads();                        // all waves done with SMEM
    bf16 (*Csh)[128] = (bf16(*)[128])&SMEM[0][0][0];  // [128 n][128 m] = 32 KB
#pragma unroll
    for (int mt = 0; mt < 2; ++mt) {
      const int tt = mh * 2 + mt;
#pragma unroll
      for (int nt = 0; nt < 2; ++nt) {
        const int nloc = nh * 64 + nt * 32 + row32;
#pragma unroll
        for (int g = 0; g < 4; ++g) {
          bf16x4 v;
#pragma unroll
          for (int j = 0; j < 4; ++j) {
            const int h = bm * 32 + tt * 8 + 4 * q2 + j;
            const float bias = (h < HS) ? b2[g * HS + h] : 0.0f;
            v[j] = (bf16)(acc[mt][nt][g * 4 + j] + bias);
          }
          *(bf16x4*)&Csh[nloc][tt * 32 + g * 8 + 4 * q2] = v;
        }
      }
    }
    __syncthreads();
#pragma unroll
    for (int i2 = 0; i2 < 8; ++i2) {
      const int idx = i2 * 256 + tid;       // 2048 x 16B, 16 chunks/row
      const int rrow = idx >> 4, off = idx & 15;
      *(u32x4*)&CbOut[(size_t)(n0 + rrow) * 4096 + bm * 128 + off * 8] =
          *(const u32x4*)&Csh[rrow][off * 8];
    }
  } else {
    __syncthreads();                        // all waves done with SMEM before overlay
    bf16 (*Hsh)[32] = (bf16(*)[32])&SMEM[0][0][0];    // [128 n][32 h] = 8 KB
#pragma unroll
    for (int mt = 0; mt < 2; ++mt) {
      const int tt = mh * 2 + mt;
#pragma unroll
      for (int nt = 0; nt < 2; ++nt) {
        const int nloc = nh * 64 + nt * 32 + row32;
        const int n = n0 + nloc;
        const int b = n >> 8;
        const int t = n & (T_ - 1);
        bf16x4 hv;
#pragma unroll
        for (int j = 0; j < 4; ++j) {
          const int h = bm * 32 + tt * 8 + 4 * q2 + j;
          const float ci = acc[mt][nt][0 + j]  + (float)cbr[mt][nt][0][j];
          const float co = acc[mt][nt][4 + j]  + (float)cbr[mt][nt][1][j];
          const float cg = acc[mt][nt][8 + j]  + (float)cbr[mt][nt][2][j];
          const float cf = acc[mt][nt][12 + j] + (float)cbr[mt][nt][3][j];
          const float ctold = (t == 0) ? cellp[b * HP + h]
                                       : (float)ctprev[(size_t)h * NT + (n - 1)];
          const float cn = sigm(cf) * ctold + sigm(ci) * tanhf(cg);
          ctnew[(size_t)h * NT + n] = (bf16)cn;
          hv[j] = (bf16)(sigm(co) * tanhf(cn));
        }
        *(bf16x4*)&Hsh[nloc][tt * 8 + 4 * q2] = hv;
      }
    }
    __syncthreads();
#pragma unroll
    for (int i2 = 0; i2 < 2; ++i2) {
      const int idx = i2 * 256 + tid;       // 512 x 16B, 4 chunks/row
      const int rrow = idx >> 2, off = idx & 3;
      *(u32x4*)&Hnew[(size_t)(n0 + rrow) * HP + bm * 32 + off * 8] =
          *(const u32x4*)&Hsh[rrow][off * 8];
    }
  }
}

// ---------------- output kernels (fp32 out) ----------------

__global__ void aux_kernel(const bf16* __restrict__ H, float* __restrict__ out, int s) {
  int idx = blockIdx.x * 256 + threadIdx.x;  // 8*256*100
  if (idx >= NT * 100) return;
  int n = idx / 100;
  int o = (idx % 100) * 4;
  int b = n >> 8, t = n & (T_ - 1);
  bf16x4 v = *(const bf16x4*)&H[(size_t)n * HP + 600 + o];
  f32x4 f = {(float)v[0], (float)v[1], (float)v[2], (float)v[3]};
  *(f32x4*)&out[AUX_OFF + ((size_t)((b * 2 + s) * T_ + t)) * 400 + o] = f;
}

__global__ void final_kernel(const bf16* __restrict__ H, const bf16* __restrict__ ct,
                             float* __restrict__ out) {
  int idx = blockIdx.x * 256 + threadIdx.x;
  if (idx < NT * 100) {
    int n = idx / 100;
    int o = (idx % 100) * 4;
    int b = n >> 8, t = n & (T_ - 1);
    bf16x4 v = *(const bf16x4*)&H[(size_t)n * HP + 600 + o];
    f32x4 f = {(float)v[0], (float)v[1], (float)v[2], (float)v[3]};
    *(f32x4*)&out[(size_t)n * 400 + o] = f;  // out_main [b][t][400]
    *(f32x4*)&out[AUX_OFF + ((size_t)((b * 2 + 1) * T_ + t)) * 400 + o] = f;
  } else {
    int j = idx - NT * 100;
    if (j < 8000) {
      int b = j / 1000, h = j % 1000;
      out[HT_OFF + j] = (float)H[(size_t)(b * T_ + 255) * HP + h];
    } else if (j < 16000) {
      int jj = j - 8000;
      int b = jj / 1000, h = jj % 1000;
      out[CT_OFF + jj] = (float)ct[(size_t)h * NT + b * T_ + 255];
    }
  }
}

// ---------------- launch ----------------

extern "C" void kernel_launch(void* const* d_in, const int* in_sizes, int n_in,
                              void* d_out, int out_size, void* d_ws, size_t ws_size,
                              hipStream_t stream) {
  const float* X    = (const float*)d_in[0];
  const float* hid  = (const float*)d_in[1];
  const float* cell = (const float*)d_in[2];
  const float* w1   = (const float*)d_in[3];
  const float* w2   = (const float*)d_in[4];
  const float* b2   = (const float*)d_in[5];
  float* out = (float*)d_out;

  char* ws = (char*)d_ws;
  size_t off = 0;
  auto alloc = [&](size_t bytes) {
    void* p = ws + off;
    off += (bytes + 255) & ~(size_t)255;
    return p;
  };
  bf16* W2q    = (bf16*)alloc((size_t)M_ * K2 * 2);     // 16 MB
  bf16* CbP    = (bf16*)alloc((size_t)NT * M_ * 2);     // 16 MB
  bf16* Hb0    = (bf16*)alloc((size_t)NT * HP * 2);     // 4 MB
  bf16* ctb0   = (bf16*)alloc((size_t)HP * NT * 2);     // 4 MB
  bf16* hidp   = (bf16*)alloc((size_t)B_ * HP * 2);
  float* cellp = (float*)alloc((size_t)B_ * HP * 4);
  // Union region: {W1q, XT} live only until the first GEMM; then {ctb1, Hb1}.
  char* R = (char*)alloc((size_t)12 * 1024 * 1024);     // 12 MB
  bf16* W1q  = (bf16*)R;                                // 8 MB
  bf16* XT   = (bf16*)(R + (size_t)8 * 1024 * 1024);    // 4 MB
  bf16* ctb1 = (bf16*)R;                                // 4 MB
  bf16* Hb1  = (bf16*)(R + (size_t)4 * 1024 * 1024);    // 4 MB

  bf16* Hb[2]  = {Hb0, Hb1};
  bf16* ctb[2] = {ctb0, ctb1};

  hipMemsetAsync(Hb[0], 0, (size_t)NT * HP * 2, stream);
  hipMemsetAsync(ctb[0], 0, (size_t)HP * NT * 2, stream);

  repack_w1<<<(M_ * K1) / 256, 256, 0, stream>>>(w1, W1q);
  repack_w2<<<(M_ * K2) / 256, 256, 0, stream>>>(w2, W2q);
  build_xt<<<(NT * K1) / 256, 256, 0, stream>>>(X, XT);
  build_hc<<<(B_ * HP) / 256, 256, 0, stream>>>(hid, cell, hidp, cellp);

  dim3 grid(NT / 128, M_ / 128);  // 16 x 32 = 512 blocks, 2/CU
  gemm_step<false><<<grid, 256, 0, stream>>>(W1q, XT, nullptr, nullptr, CbP, b2,
                                             nullptr, nullptr, nullptr, nullptr, K1);
  for (int i = 0; i < 40; ++i) {
    int p = i & 1;
    gemm_step<true><<<grid, 256, 0, stream>>>(W2q, Hb[p], hidp, CbP, nullptr, nullptr,
                                              ctb[p], cellp, ctb[p ^ 1], Hb[p ^ 1], K2);
    if (i == 19) aux_kernel<<<800, 256, 0, stream>>>(Hb[p ^ 1], out, 0);
  }
  final_kernel<<<(NT * 100 + 16000 + 255) / 256, 256, 0, stream>>>(Hb[0], ctb[0], out);
}

// Round 11
// 1999.126 us; speedup vs baseline: 1.2120x; 1.2120x over previous
//
#include <hip/hip_runtime.h>
#include <hip/hip_bf16.h>
#include <math.h>

typedef __bf16 bf16;
typedef __bf16 bf16x8 __attribute__((ext_vector_type(8)));
typedef __bf16 bf16x4 __attribute__((ext_vector_type(4)));
typedef float f32x4 __attribute__((ext_vector_type(4)));
typedef unsigned int u32;
typedef u32 u32x4 __attribute__((ext_vector_type(4)));

#define NINP 400
#define HS   1000
#define HP   1024
#define B_   8
#define T_   256
#define NT   2048   /* B_*T_ */
#define K2   2048   /* 2*HP  */
#define K1   1024   /* 2*512 */
#define M_   4096   /* 4 gates * HP */

#define HT_OFF   819200
#define CT_OFF   827200
#define AUX_OFF  835200

typedef __attribute__((address_space(1))) const void gvoid;
typedef __attribute__((address_space(3))) void lvoid;

__device__ __forceinline__ void async_copy16(void* lds, const void* g) {
  __builtin_amdgcn_global_load_lds((gvoid*)g, (lvoid*)lds, 16, 0, 0);
}

__device__ __forceinline__ float sigm(float x) { return 1.0f / (1.0f + expf(-x)); }

// ---------------- repack kernels (fp32 inputs -> packed-m bf16) ----------------
// M-packing for 128-row blocks of 2x2 waves with 16x16 tiles:
//   pm = (h>>5)*128 + ((h>>4)&1)*64 + g*16 + (h&15)
// Block bm covers h in [bm*32, bm*32+32); wave mh's 4 m-tiles = gates 0..3 of
// h-group mh. C-layout (16x16): col=lane&15, row=quad*4+reg -> all 4 gates of a
// given h land in the same lane/reg across acc[0..3] -> lane-local gating.

__global__ void repack_w1(const float* __restrict__ w1, bf16* __restrict__ W1q) {
  int idx = blockIdx.x * 256 + threadIdx.x;           // 4096*1024
  if (idx >= M_ * K1) return;
  int pm = idx >> 10, k = idx & 1023;
  int g = (pm >> 4) & 3;
  int h = (pm >> 7) * 32 + ((pm >> 6) & 1) * 16 + (pm & 15);
  float v = 0.0f;
  if (h < HS) {
    int c = g * HS + h;
    if (k < 512) { if (k < NINP) v = w1[(size_t)c * (NINP * 2) + k * 2 + 0]; }
    else { int j = k - 512; if (j < NINP) v = w1[(size_t)c * (NINP * 2) + j * 2 + 1]; }
  }
  W1q[idx] = (bf16)v;
}

__global__ void repack_w2(const float* __restrict__ w2, bf16* __restrict__ W2q) {
  int idx = blockIdx.x * 256 + threadIdx.x;           // 4096*2048
  if (idx >= M_ * K2) return;
  int pm = idx >> 11, k = idx & 2047;
  int g = (pm >> 4) & 3;
  int h = (pm >> 7) * 32 + ((pm >> 6) & 1) * 16 + (pm & 15);
  float v = 0.0f;
  if (h < HS) {
    int c = g * HS + h;
    if (k < HP) { if (k < HS) v = w2[(size_t)c * (HS * 2) + k * 2 + 0]; }
    else { int j = k - HP; if (j < HS) v = w2[(size_t)c * (HS * 2) + j * 2 + 1]; }
  }
  W2q[idx] = (bf16)v;
}

__global__ void build_xt(const float* __restrict__ X, bf16* __restrict__ XT) {
  int idx = blockIdx.x * 256 + threadIdx.x;           // 2048*1024
  if (idx >= NT * K1) return;
  int n = idx >> 10, k = idx & 1023;
  int b = n >> 8, t = n & (T_ - 1);
  float v = 0.0f;
  if (k < 512) { if (k < NINP && t > 0) v = X[((size_t)b * NINP + k) * T_ + t - 1]; }
  else { int j = k - 512; if (j < NINP) v = X[((size_t)b * NINP + j) * T_ + t]; }
  XT[idx] = (bf16)v;
}

__global__ void build_hc(const float* __restrict__ hid, const float* __restrict__ cell,
                         bf16* __restrict__ hidp, float* __restrict__ cellp) {
  int idx = blockIdx.x * 256 + threadIdx.x;           // 8*1024
  if (idx >= B_ * HP) return;
  int b = idx >> 10, k = idx & (HP - 1);
  hidp[idx]  = (k < HS) ? (bf16)hid[b * HS + k] : (bf16)0.0f;
  cellp[idx] = (k < HS) ? cell[b * HS + k] : 0.0f;
}

// ---------------- fused GEMM (+gating), 16x16x32 MFMA, 2x2 waves of 64x64 ----------------
// Block 128M x 128N, 4 waves; wave (mh,nh) owns 64x64 as 4mt x 4nt 16x16 tiles:
// 8 ds_read_b128 per 16 MFMA -- half of r6's LDS bytes/MAC, using ONLY r6's
// proven conflict-free fragment idiom (row = col + 16*tile, chunk =
// ((kc>>3)+quad+row)&7). BK=64, single-buffered As/Bs (32 KB), r6's verified
// 2-barrier DMA staging with r5 source-rotation (swo).

template <bool GATED>
__global__ __launch_bounds__(256, 2) void gemm_step(
    const bf16* __restrict__ A,      // W2q [4096][2048] or W1q [4096][1024] packed-m
    const bf16* __restrict__ Bsrc,   // gated: Hprev [NT][HP]; plain: XT [NT][K1]
    const bf16* __restrict__ hidp,   // [B_][HP]
    const bf16* __restrict__ CbIn,   // gated: CbP [NT][4096] packed-m
    bf16* __restrict__ CbOut,        // plain: write CbP
    const float* __restrict__ b2,
    const bf16* __restrict__ ctprev, // [HP][NT]
    const float* __restrict__ cellp, // [B_][HP]
    bf16* __restrict__ ctnew,        // [HP][NT]
    bf16* __restrict__ Hnew,         // [NT][HP]
    int K) {
  __shared__ bf16 SMEM[2][128][64];  // [0]=As, [1]=Bs; 32 KB; epilogue overlays

  const int tid = threadIdx.x;
  const int lane = tid & 63;
  const int w = tid >> 6;
  const int mh = w >> 1, nh = w & 1;
  const int dr = lane >> 3, c8 = lane & 7;
  const int swo = ((c8 - dr) & 7) * 8;     // staging source permutation (r5)
  const int quad = lane >> 4, col = lane & 15;

  int n0, bm;
  if (GATED) {
    const int L = blockIdx.y * gridDim.x + blockIdx.x;
    bm = (L & 7) * 4 + (L >> 7);           // XCD L&7 owns 4 bm (2 MB W2q slice)
    n0 = ((L >> 3) & 15) * 128;
  } else {
    n0 = blockIdx.x * 128;
    bm = blockIdx.y;
  }

  f32x4 acc[4][4];
#pragma unroll
  for (int i = 0; i < 4; ++i)
#pragma unroll
    for (int j = 0; j < 4; ++j) acc[i][j] = (f32x4){0.f, 0.f, 0.f, 0.f};

  const int NIT = K >> 6;
  for (int it = 0; it < NIT; ++it) {
    const int k0 = it << 6;
    __syncthreads();                        // prev compute done; buffers reusable
#pragma unroll
    for (int inst = 0; inst < 4; ++inst) {
      const int r = inst * 32 + w * 8 + dr;
      // A staging: packed-m rows bm*128 + r
      async_copy16(&SMEM[0][inst * 32 + w * 8][0],
                   A + (size_t)(bm * 128 + r) * K + k0 + swo);
      // B staging
      const int n = n0 + r;
      const bf16* bp;
      if (GATED) {
        const int kk = (k0 & (HP - 1)) + swo;
        if (k0 < HP) {
          const int t = n & (T_ - 1);
          bp = (t == 0) ? (hidp + (size_t)(n >> 8) * HP + kk)
                        : (Bsrc + (size_t)(n - 1) * HP + kk);
        } else {
          bp = Bsrc + (size_t)n * HP + kk;
        }
      } else {
        bp = Bsrc + (size_t)n * K + k0 + swo;
      }
      async_copy16(&SMEM[1][inst * 32 + w * 8][0], bp);
    }
    __syncthreads();                        // DMA drained
#pragma unroll
    for (int kc = 0; kc < 64; kc += 32) {
      bf16x8 av[4], bv[4];
#pragma unroll
      for (int mt = 0; mt < 4; ++mt) {
        const int rA = mh * 64 + mt * 16 + col;
        av[mt] = *(const bf16x8*)&SMEM[0][rA][(((kc >> 3) + quad + rA) & 7) * 8];
      }
#pragma unroll
      for (int nt = 0; nt < 4; ++nt) {
        const int rB = nh * 64 + nt * 16 + col;
        bv[nt] = *(const bf16x8*)&SMEM[1][rB][(((kc >> 3) + quad + rB) & 7) * 8];
      }
#pragma unroll
      for (int mt = 0; mt < 4; ++mt)
#pragma unroll
        for (int nt = 0; nt < 4; ++nt)
          acc[mt][nt] = __builtin_amdgcn_mfma_f32_16x16x32_bf16(av[mt], bv[nt], acc[mt][nt], 0, 0, 0);
    }
  }

  if (!GATED) {
    __syncthreads();                        // all waves done with SMEM
    bf16 (*Csh)[128] = (bf16(*)[128])&SMEM[0][0][0];  // [128 n][128 pm] = 32 KB
#pragma unroll
    for (int mt = 0; mt < 4; ++mt) {        // mt = gate
#pragma unroll
      for (int nt = 0; nt < 4; ++nt) {
        const int nloc = nh * 64 + nt * 16 + col;
        bf16x4 v;
#pragma unroll
        for (int j = 0; j < 4; ++j) {
          const int h = bm * 32 + mh * 16 + quad * 4 + j;
          const float bias = (h < HS) ? b2[mt * HS + h] : 0.0f;
          v[j] = (bf16)(acc[mt][nt][j] + bias);
        }
        *(bf16x4*)&Csh[nloc][mh * 64 + mt * 16 + quad * 4] = v;
      }
    }
    __syncthreads();
#pragma unroll
    for (int i2 = 0; i2 < 8; ++i2) {
      const int idx = i2 * 256 + tid;       // 2048 x 16B, 16 chunks/row
      const int rrow = idx >> 4, off = idx & 15;
      *(u32x4*)&CbOut[(size_t)(n0 + rrow) * 4096 + bm * 128 + off * 8] =
          *(const u32x4*)&Csh[rrow][off * 8];
    }
  } else {
    __syncthreads();                        // all waves done with SMEM before overlay
    bf16 (*Hsh)[32] = (bf16(*)[32])&SMEM[0][0][0];    // [128 n][32 h] = 8 KB
#pragma unroll
    for (int nt = 0; nt < 4; ++nt) {
      const int nloc = nh * 64 + nt * 16 + col;
      const int n = n0 + nloc;
      const int b = n >> 8;
      const int t = n & (T_ - 1);
      const size_t cb = (size_t)n * 4096 + (size_t)(bm * 2 + mh) * 64 + quad * 4;
      bf16x4 c0 = *(const bf16x4*)&CbIn[cb + 0];
      bf16x4 c1 = *(const bf16x4*)&CbIn[cb + 16];
      bf16x4 c2 = *(const bf16x4*)&CbIn[cb + 32];
      bf16x4 c3 = *(const bf16x4*)&CbIn[cb + 48];
      bf16x4 hv;
#pragma unroll
      for (int j = 0; j < 4; ++j) {
        const int h = bm * 32 + mh * 16 + quad * 4 + j;
        const float ci = acc[0][nt][j] + (float)c0[j];
        const float co = acc[1][nt][j] + (float)c1[j];
        const float cg = acc[2][nt][j] + (float)c2[j];
        const float cf = acc[3][nt][j] + (float)c3[j];
        const float ctold = (t == 0) ? cellp[b * HP + h]
                                     : (float)ctprev[(size_t)h * NT + (n - 1)];
        const float cn = sigm(cf) * ctold + sigm(ci) * tanhf(cg);
        ctnew[(size_t)h * NT + n] = (bf16)cn;
        hv[j] = (bf16)(sigm(co) * tanhf(cn));
      }
      *(bf16x4*)&Hsh[nloc][mh * 16 + quad * 4] = hv;
    }
    __syncthreads();
#pragma unroll
    for (int i2 = 0; i2 < 2; ++i2) {
      const int idx = i2 * 256 + tid;       // 512 x 16B, 4 chunks/row
      const int rrow = idx >> 2, off = idx & 3;
      *(u32x4*)&Hnew[(size_t)(n0 + rrow) * HP + bm * 32 + off * 8] =
          *(const u32x4*)&Hsh[rrow][off * 8];
    }
  }
}

// ---------------- output kernels (fp32 out) ----------------

__global__ void aux_kernel(const bf16* __restrict__ H, float* __restrict__ out, int s) {
  int idx = blockIdx.x * 256 + threadIdx.x;  // 8*256*100
  if (idx >= NT * 100) return;
  int n = idx / 100;
  int o = (idx % 100) * 4;
  int b = n >> 8, t = n & (T_ - 1);
  bf16x4 v = *(const bf16x4*)&H[(size_t)n * HP + 600 + o];
  f32x4 f = {(float)v[0], (float)v[1], (float)v[2], (float)v[3]};
  *(f32x4*)&out[AUX_OFF + ((size_t)((b * 2 + s) * T_ + t)) * 400 + o] = f;
}

__global__ void final_kernel(const bf16* __restrict__ H, const bf16* __restrict__ ct,
                             float* __restrict__ out) {
  int idx = blockIdx.x * 256 + threadIdx.x;
  if (idx < NT * 100) {
    int n = idx / 100;
    int o = (idx % 100) * 4;
    int b = n >> 8, t = n & (T_ - 1);
    bf16x4 v = *(const bf16x4*)&H[(size_t)n * HP + 600 + o];
    f32x4 f = {(float)v[0], (float)v[1], (float)v[2], (float)v[3]};
    *(f32x4*)&out[(size_t)n * 400 + o] = f;  // out_main [b][t][400]
    *(f32x4*)&out[AUX_OFF + ((size_t)((b * 2 + 1) * T_ + t)) * 400 + o] = f;
  } else {
    int j = idx - NT * 100;
    if (j < 8000) {
      int b = j / 1000, h = j % 1000;
      out[HT_OFF + j] = (float)H[(size_t)(b * T_ + 255) * HP + h];
    } else if (j < 16000) {
      int jj = j - 8000;
      int b = jj / 1000, h = jj % 1000;
      out[CT_OFF + jj] = (float)ct[(size_t)h * NT + b * T_ + 255];
    }
  }
}

// ---------------- launch ----------------

extern "C" void kernel_launch(void* const* d_in, const int* in_sizes, int n_in,
                              void* d_out, int out_size, void* d_ws, size_t ws_size,
                              hipStream_t stream) {
  const float* X    = (const float*)d_in[0];
  const float* hid  = (const float*)d_in[1];
  const float* cell = (const float*)d_in[2];
  const float* w1   = (const float*)d_in[3];
  const float* w2   = (const float*)d_in[4];
  const float* b2   = (const float*)d_in[5];
  float* out = (float*)d_out;

  char* ws = (char*)d_ws;
  size_t off = 0;
  auto alloc = [&](size_t bytes) {
    void* p = ws + off;
    off += (bytes + 255) & ~(size_t)255;
    return p;
  };
  bf16* W2q    = (bf16*)alloc((size_t)M_ * K2 * 2);     // 16 MB
  bf16* CbP    = (bf16*)alloc((size_t)NT * M_ * 2);     // 16 MB
  bf16* Hb0    = (bf16*)alloc((size_t)NT * HP * 2);     // 4 MB
  bf16* ctb0   = (bf16*)alloc((size_t)HP * NT * 2);     // 4 MB
  bf16* hidp   = (bf16*)alloc((size_t)B_ * HP * 2);
  float* cellp = (float*)alloc((size_t)B_ * HP * 4);
  // Union region: {W1q, XT} live only until the first GEMM; then {ctb1, Hb1}.
  char* R = (char*)alloc((size_t)12 * 1024 * 1024);     // 12 MB
  bf16* W1q  = (bf16*)R;                                // 8 MB
  bf16* XT   = (bf16*)(R + (size_t)8 * 1024 * 1024);    // 4 MB
  bf16* ctb1 = (bf16*)R;                                // 4 MB
  bf16* Hb1  = (bf16*)(R + (size_t)4 * 1024 * 1024);    // 4 MB

  bf16* Hb[2]  = {Hb0, Hb1};
  bf16* ctb[2] = {ctb0, ctb1};

  hipMemsetAsync(Hb[0], 0, (size_t)NT * HP * 2, stream);
  hipMemsetAsync(ctb[0], 0, (size_t)HP * NT * 2, stream);

  repack_w1<<<(M_ * K1) / 256, 256, 0, stream>>>(w1, W1q);
  repack_w2<<<(M_ * K2) / 256, 256, 0, stream>>>(w2, W2q);
  build_xt<<<(NT * K1) / 256, 256, 0, stream>>>(X, XT);
  build_hc<<<(B_ * HP) / 256, 256, 0, stream>>>(hid, cell, hidp, cellp);

  dim3 grid(NT / 128, M_ / 128);  // 16 x 32 = 512 blocks, 2/CU
  gemm_step<false><<<grid, 256, 0, stream>>>(W1q, XT, nullptr, nullptr, CbP, b2,
                                             nullptr, nullptr, nullptr, nullptr, K1);
  for (int i = 0; i < 40; ++i) {
    int p = i & 1;
    gemm_step<true><<<grid, 256, 0, stream>>>(W2q, Hb[p], hidp, CbP, nullptr, nullptr,
                                              ctb[p], cellp, ctb[p ^ 1], Hb[p ^ 1], K2);
    if (i == 19) aux_kernel<<<800, 256, 0, stream>>>(Hb[p ^ 1], out, 0);
  }
  final_kernel<<<(NT * 100 + 16000 + 255) / 256, 256, 0, stream>>>(Hb[0], ctb[0], out);
}